// Round 19
// baseline (4388.647 us; speedup 1.0000x reference)
//
#include <hip/hip_runtime.h>
#include <hip/hip_bf16.h>
#include <stdint.h>

#define Tn 512
#define Bn 64
#define Hn 512
#define LDP 520           // LDS row pitch (u16): 1040B
#define NWG 128
#define NTHR 512
#define BnHn (Bn * Hn)

typedef unsigned short u16;
typedef unsigned int u32;
typedef unsigned long long u64;
typedef __attribute__((ext_vector_type(8))) short bf16x8;
typedef __attribute__((ext_vector_type(4))) float f32x4;

// ws layout (bytes):
//   0     : flags[4][32] u32 (R18 fallback barrier)          512B
//   16384 : smode: hstamp u64[513 slot][2 layer][64 samp][256 unit]  (~128.2 MiB)
//           else : hist bf16 [nslot][2][Bn][Hn] (R18 layout)
//   after : xbf [Tn][Bn][Hn] bf16 (32MB), if xok
#define HIST_OFF 16384
#define STAMP_BYTES 134479872ULL   // 513*2*64*256*8

__device__ __forceinline__ u16 f2bf(float f) {
  u32 u = __float_as_uint(f);
  u = (u + 0x7FFFu + ((u >> 16) & 1u)) >> 16;   // RNE
  return (u16)u;
}
__device__ __forceinline__ float sigf(float x) { return 1.f / (1.f + __expf(-x)); }
__device__ __forceinline__ float mytanh(float x) {
  float e = __expf(2.f * x);
  return 1.f - 2.f / (e + 1.f);
}
__device__ __forceinline__ u32 ald32(const u32* p) {
  return __hip_atomic_load(p, __ATOMIC_RELAXED, __HIP_MEMORY_SCOPE_AGENT);
}
__device__ __forceinline__ u64 ald64(const u64* p) {
  return __hip_atomic_load(p, __ATOMIC_RELAXED, __HIP_MEMORY_SCOPE_AGENT);
}

// ---------- pre-kernel: x -> bf16, hx -> init slot ----------
extern "C" __global__ void __launch_bounds__(256)
lstm_prep(const float* __restrict__ x, const float* __restrict__ hx,
          u32* __restrict__ ws, int xok, int smode, int histok) {
  u16* hist = (u16*)((char*)ws + HIST_OFF);
  u64* hstamp = (u64*)((char*)ws + HIST_OFF);
  u16* xbf = smode ? (u16*)((char*)ws + HIST_OFF + STAMP_BYTES)
                   : hist + (size_t)(histok ? 513 : 8) * 2 * BnHn;
  const int gt = blockIdx.x * 256 + threadIdx.x;   // 0..524287
  if (xok) {
#pragma unroll
    for (int i = 0; i < 8; ++i) {
      const int c = gt + (i << 19);                // float4 chunk id, 4194304 total
      const float4 v = *(const float4*)(x + (size_t)c * 4);
      const u64 pk = (u64)((u32)f2bf(v.x) | ((u32)f2bf(v.y) << 16)) |
                     ((u64)((u32)f2bf(v.z) | ((u32)f2bf(v.w) << 16)) << 32);
      *(u64*)(xbf + (size_t)c * 4) = pk;
    }
  }
  if (gt < 32768) {
    const int e0 = 2 * gt;
    const int l = e0 >> 15;
    const int off = e0 & 32767;
    const u32 pk = (u32)f2bf(hx[e0]) | ((u32)f2bf(hx[e0 + 1]) << 16);
    if (smode) {
      const int b = off >> 9;            // global sample 0..63
      const int unit = (off & 511) >> 1; // 0..255
      hstamp[((size_t)512 * 2 + l) * 16384 + (size_t)b * 256 + unit] =
          (u64)pk | (15ULL << 32);       // stamp = (-1)+16
    } else {
      const int slot_init = histok ? 512 : 7;
      *(u32*)(hist + ((size_t)slot_init * 2 + l) * BnHn + off) = pk;
    }
  }
}

// ---------- main persistent cooperative kernel ----------
extern "C" __global__ void __launch_bounds__(NTHR, 1)
lstm_fused(const float* __restrict__ x, const float* __restrict__ hx,
           const float* __restrict__ cx, const float* __restrict__ Wih,
           const float* __restrict__ Whh, const float* __restrict__ bih,
           const float* __restrict__ bhh, float* __restrict__ out,
           u32* __restrict__ ws, int xok, int smode, int histok) {
  __shared__ u16 sh_inp[32 * LDP];
  __shared__ u16 sh_h[32 * LDP];

  // one-time L1/L2 invalidate: drop lines poisoned (0xAA) between launches
  __builtin_amdgcn_fence(__ATOMIC_ACQUIRE, "agent");

  const int wg = blockIdx.x;
  const int tid = threadIdx.x;
  const int layer = wg >> 6;        // 0..1
  const int rem = wg & 63;
  const int shalf = rem >> 5;       // batch half: samples 0-31 / 32-63
  const int cc = rem & 31;          // 16-column chunk
  const int wave = tid >> 6;        // 0..7
  const int lane = tid & 63;
  const int l15 = lane & 15;
  const int lhi = lane >> 4;
  const int mt = wave >> 1;         // 0..3 gate-row tile
  const int nt = wave & 1;          // 0..1 sample tile

  u32* flags = ws;
  u16* hist  = (u16*)((char*)ws + HIST_OFF);
  u64* hstamp = (u64*)((char*)ws + HIST_OFF);
  u16* xbf = smode ? (u16*)((char*)ws + HIST_OFF + STAMP_BYTES)
                   : hist + (size_t)(histok ? 513 : 8) * 2 * BnHn;
  const int init_slot = histok ? 512 : 7;
  const int gid = layer * 2 + shalf;

  // ---- weights -> registers. WG rows (64): j = col*4 + gate, col base cc*16 ----
  const int jrow = mt * 16 + l15;
  const int gateA = jrow & 3, colA = jrow >> 2;
  const int growA = gateA * Hn + cc * 16 + colA;
  const float* wihp = Wih + ((size_t)layer * 4 * Hn + growA) * Hn;
  const float* whhp = Whh + ((size_t)layer * 4 * Hn + growA) * Hn;
  bf16x8 wih_f[16], whh_f[16];
#pragma unroll
  for (int kt = 0; kt < 16; ++kt) {
    const int k0 = kt * 32 + lhi * 8;
    const float4 va0 = *(const float4*)(wihp + k0);
    const float4 va1 = *(const float4*)(wihp + k0 + 4);
    const float4 vb0 = *(const float4*)(whhp + k0);
    const float4 vb1 = *(const float4*)(whhp + k0 + 4);
    bf16x8 a, b;
    a[0]=(short)f2bf(va0.x); a[1]=(short)f2bf(va0.y); a[2]=(short)f2bf(va0.z); a[3]=(short)f2bf(va0.w);
    a[4]=(short)f2bf(va1.x); a[5]=(short)f2bf(va1.y); a[6]=(short)f2bf(va1.z); a[7]=(short)f2bf(va1.w);
    b[0]=(short)f2bf(vb0.x); b[1]=(short)f2bf(vb0.y); b[2]=(short)f2bf(vb0.z); b[3]=(short)f2bf(vb0.w);
    b[4]=(short)f2bf(vb1.x); b[5]=(short)f2bf(vb1.y); b[6]=(short)f2bf(vb1.z); b[7]=(short)f2bf(vb1.w);
    wih_f[kt] = a; whh_f[kt] = b;
  }

  // ---- elementwise lane mapping: acc reg r == gate r for (sampE, colE) ----
  const int colE = cc * 16 + mt * 4 + lhi;
  const int sampE = shalf * 32 + nt * 16 + l15;
  float bias[4];
#pragma unroll
  for (int r = 0; r < 4; ++r) {
    const int grow = r * Hn + cc * 16 + mt * 4 + lhi;
    bias[r] = bih[layer * 4 * Hn + grow] + bhh[layer * 4 * Hn + grow];
  }
  float c_cur = cx[((size_t)layer * Bn + sampE) * Hn + colE];

  // stage x(t) -> sh_inp (layer 0); plain loads, coherent via prep boundary
  auto stage_x = [&](int t) {
    if (xok) {
      const u16* ip = xbf + ((size_t)t * Bn + shalf * 32) * Hn;
#pragma unroll
      for (int i = 0; i < 4; ++i) {
        const int chunk = tid + i * 512;
        const int row = chunk >> 6, c0 = (chunk & 63) * 8;
        const uint4 v = *(const uint4*)(ip + (size_t)row * Hn + c0);
        *(uint4*)(&sh_inp[row * LDP + c0]) = v;
      }
    } else {
      const float* xp = x + ((size_t)t * Bn + shalf * 32) * Hn;
#pragma unroll
      for (int i = 0; i < 8; ++i) {
        const int chunk = tid + i * 512;
        const int row = chunk >> 7, c0 = (chunk & 127) * 4;
        const float4 v = *(const float4*)(xp + (size_t)row * Hn + c0);
        const u32 p0 = (u32)f2bf(v.x) | ((u32)f2bf(v.y) << 16);
        const u32 p1 = (u32)f2bf(v.z) | ((u32)f2bf(v.w) << 16);
        *(uint2*)(&sh_inp[row * LDP + c0]) = make_uint2(p0, p1);
      }
    }
  };
  // ih-GEMM from sh_inp into persistent accumulators (shadow-phase compute)
  f32x4 aI0 = {0.f,0.f,0.f,0.f}, aI1 = {0.f,0.f,0.f,0.f};
  auto compute_aI = [&]() {
    f32x4 t0 = {0.f,0.f,0.f,0.f}, t1 = {0.f,0.f,0.f,0.f};
    const int brow = (nt * 16 + l15) * LDP;
#pragma unroll
    for (int kt = 0; kt < 16; kt += 2) {
      const bf16x8 bi0 = *(const bf16x8*)(&sh_inp[brow + kt * 32 + lhi * 8]);
      const bf16x8 bi1 = *(const bf16x8*)(&sh_inp[brow + (kt + 1) * 32 + lhi * 8]);
      t0 = __builtin_amdgcn_mfma_f32_16x16x32_bf16(wih_f[kt], bi0, t0, 0, 0, 0);
      t1 = __builtin_amdgcn_mfma_f32_16x16x32_bf16(wih_f[kt + 1], bi1, t1, 0, 0, 0);
    }
    aI0 = t0; aI1 = t1;
  };
  // hh-GEMM + elementwise + out; returns via refs
  auto do_compute = [&](int t, float& hn, float& cn) {
    f32x4 b0 = {0,0,0,0}, b1 = {0,0,0,0};
    const int brow = (nt * 16 + l15) * LDP;
#pragma unroll
    for (int kt = 0; kt < 16; kt += 2) {
      const bf16x8 bh0 = *(const bf16x8*)(&sh_h[brow + kt * 32 + lhi * 8]);
      const bf16x8 bh1 = *(const bf16x8*)(&sh_h[brow + (kt + 1) * 32 + lhi * 8]);
      b0 = __builtin_amdgcn_mfma_f32_16x16x32_bf16(whh_f[kt], bh0, b0, 0, 0, 0);
      b1 = __builtin_amdgcn_mfma_f32_16x16x32_bf16(whh_f[kt + 1], bh1, b1, 0, 0, 0);
    }
    const float gi = aI0[0] + aI1[0] + b0[0] + b1[0] + bias[0];
    const float gf = aI0[1] + aI1[1] + b0[1] + b1[1] + bias[1];
    const float gg = aI0[2] + aI1[2] + b0[2] + b1[2] + bias[2];
    const float go_ = aI0[3] + aI1[3] + b0[3] + b1[3] + bias[3];
    cn = sigf(gf) * c_cur + sigf(gi) * mytanh(gg);
    hn = sigf(go_) * mytanh(cn);
    c_cur = cn;
  };

  if (smode) {
    // ================= stamped monotonic dataflow (no barrier) =================
    // stamped restage: plain uint4 fast path (L2) + per-unit agent spin fallback
    auto stage_stamped = [&](int slot, int srclayer, u32 expect, u16* dst) {
      u64* base = hstamp + ((size_t)slot * 2 + srclayer) * 16384 + (size_t)(shalf * 32) * 256;
#pragma unroll
      for (int i = 0; i < 8; ++i) {
        const int p = tid + i * 512;
        const int samp = p >> 7, up = p & 127;
        const u64* a = base + samp * 256 + 2 * up;
        uint4 v = *(const uint4*)a;           // plain: L2-cacheable fast path
        if (v.y != expect || v.w != expect) { // late units: LLC-direct spins
          u64 q0, q1;
          do { q0 = ald64(a); } while ((u32)(q0 >> 32) != expect);
          do { q1 = ald64(a + 1); } while ((u32)(q1 >> 32) != expect);
          v.x = (u32)q0; v.z = (u32)q1;
        }
        *(uint2*)(&dst[samp * LDP + 4 * up]) = make_uint2(v.x, v.z);
      }
    };

    if (layer == 0) stage_x(0);
    __syncthreads();
    if (layer == 0) compute_aI();

    const int smax = Tn + 2;         // L1 lags 3 (t = s-3); L0 idles s >= Tn
    for (int s = 0; s <= smax; ++s) {
      const int t = layer ? s - 3 : s;
      const bool act = (t >= 0) && (t < Tn);

      if (act) {
        // gate + restage own h(t-1): slot (t==0 ? 512 : t-1), stamp t+15
        const int slotR = (t == 0) ? 512 : (t - 1);
        stage_stamped(slotR, layer, (u32)(t + 15), sh_h);
      }
      __syncthreads();

      if (act) {
        float hn, cn;
        do_compute(t, hn, cn);
        // self-flagging h store: {2 cols, stamp t+16}; fire-and-forget (NO drain)
        const u32 hu = (u32)f2bf(hn);
        const u32 pair = hu | (__shfl_xor(hu, 16) << 16);
        if ((lhi & 1) == 0) {
          const int unit = cc * 8 + mt * 2 + (lhi >> 1);
          u64* wp = hstamp + ((size_t)t * 2 + layer) * 16384 + (size_t)sampE * 256 + unit;
          __hip_atomic_store(wp, (u64)pair | ((u64)(u32)(t + 16) << 32),
                             __ATOMIC_RELAXED, __HIP_MEMORY_SCOPE_AGENT);
        }
        if (layer == 1)
          out[((size_t)t * Bn + sampE) * Hn + colE] = hn;
        if (t == Tn - 1) {
          out[(size_t)Tn * Bn * Hn + ((size_t)layer * Bn + sampE) * Hn + colE] = hn;
          out[(size_t)Tn * Bn * Hn + (size_t)2 * Bn * Hn + ((size_t)layer * Bn + sampE) * Hn + colE] = cn;
        }
      }
      // shadow: next-step input staging (stamp-gated for L1) + ih-GEMM
      bool ihnext = false;
      if (layer == 0) {
        if (s + 1 < Tn) { stage_x(s + 1); ihnext = true; }
      } else {
        const int u = s - 2;
        if (u >= 0 && u < Tn) { stage_stamped(u, 0, (u32)(u + 16), sh_inp); ihnext = true; }
      }
      __syncthreads();
      if (ihnext) compute_aI();
    }
    return;
  }

  // ================= R18 fallback: packed-flag flat barrier =================
  auto stage_h = [&](int slot, int srclayer, u16* dst) {
    const u16* hp = hist + ((size_t)slot * 2 + srclayer) * BnHn + (size_t)(shalf * 32) * Hn;
    if (histok) {
#pragma unroll
      for (int i = 0; i < 4; ++i) {
        const int chunk = tid + i * 512;
        const int row = chunk >> 6, c0 = (chunk & 63) * 8;
        const uint4 v = *(const uint4*)(hp + (size_t)row * Hn + c0);
        *(uint4*)(&dst[row * LDP + c0]) = v;
      }
    } else {
#pragma unroll
      for (int i = 0; i < 8; ++i) {
        const int chunk = tid + i * 512;
        const int row = chunk >> 7, c0 = (chunk & 127) * 4;
        const u64 v = ald64((const u64*)(hp + (size_t)row * Hn + c0));
        *(u64*)(&dst[row * LDP + c0]) = v;
      }
    }
  };
  int pidx, tgtoff;
  if (layer == 0) {
    if (lane < 32) { pidx = (0 * 2 + shalf) * 32 + lane; tgtoff = 0; }
    else if (histok) { pidx = (0 * 2 + shalf) * 32 + (lane - 32); tgtoff = 0; }
    else { pidx = (1 * 2 + shalf) * 32 + (lane - 32); tgtoff = 1; }
  } else {
    if (lane < 32) { pidx = (1 * 2 + shalf) * 32 + lane; tgtoff = 0; }
    else { pidx = (0 * 2 + shalf) * 32 + (lane - 32); tgtoff = 1; }
  }
  const u32* pollp = &flags[pidx];

  if (layer == 0) stage_x(0);
  __syncthreads();
  if (layer == 0) compute_aI();

  const int smax = Tn + 2;
  u32 ep = 0;
  for (int s = 0; s <= smax; ++s) {
    const int t = layer ? s - 3 : s;
    const bool act = (t >= 0) && (t < Tn);

    if (act) {
      const int slotR = (t == 0) ? init_slot : (histok ? (t - 1) : ((t - 1) & 7));
      stage_h(slotR, layer, sh_h);
    }
    __syncthreads();

    if (act) {
      float hn, cn;
      do_compute(t, hn, cn);
      const u32 hu = (u32)f2bf(hn);
      const u32 pair = hu | (__shfl_xor(hu, 16) << 16);
      const u32 hi2 = __shfl_xor(pair, 32);
      if (lhi == 0) {
        const int slotW = histok ? t : (t & 7);
        const u64 v8 = (u64)pair | ((u64)hi2 << 32);
        u16* wp = hist + ((size_t)slotW * 2 + layer) * BnHn + (size_t)sampE * Hn + cc * 16 + mt * 4;
        __hip_atomic_store((u64*)wp, v8, __ATOMIC_RELAXED, __HIP_MEMORY_SCOPE_AGENT);
      }
      if (layer == 1)
        out[((size_t)t * Bn + sampE) * Hn + colE] = hn;
      if (t == Tn - 1) {
        out[(size_t)Tn * Bn * Hn + ((size_t)layer * Bn + sampE) * Hn + colE] = hn;
        out[(size_t)Tn * Bn * Hn + (size_t)2 * Bn * Hn + ((size_t)layer * Bn + sampE) * Hn + colE] = cn;
      }
    }
    asm volatile("s_waitcnt vmcnt(0)" ::: "memory");
    __syncthreads();
    ++ep;
    if (tid == 0)
      __hip_atomic_store(&flags[gid * 32 + cc], ep,
                         __ATOMIC_RELAXED, __HIP_MEMORY_SCOPE_AGENT);

    bool ihnext = false;
    if (layer == 0) {
      if (s + 1 < Tn) { stage_x(s + 1); ihnext = true; }
    } else {
      const int u = s - 2;
      if (u >= 0 && u < Tn) {
        const int slotI = histok ? u : (u & 7);
        stage_h(slotI, 0, sh_inp);
        ihnext = true;
      }
    }
    __syncthreads();
    if (ihnext) compute_aI();

    if (s == smax) break;

    while (true) {
      const u32 v = ald32(pollp);
      if (__all((int)(v + (u32)tgtoff >= ep))) break;
    }
    asm volatile("" ::: "memory");
  }
}

extern "C" void kernel_launch(void* const* d_in, const int* in_sizes, int n_in,
                              void* d_out, int out_size, void* d_ws, size_t ws_size,
                              hipStream_t stream) {
  const float* x   = (const float*)d_in[0];
  const float* hx  = (const float*)d_in[1];
  const float* cx  = (const float*)d_in[2];
  const float* Wih = (const float*)d_in[3];
  const float* Whh = (const float*)d_in[4];
  const float* bih = (const float*)d_in[5];
  const float* bhh = (const float*)d_in[6];
  float* outp = (float*)d_out;
  u32* wsp = (u32*)d_ws;

  const size_t xbytes = (size_t)Tn * Bn * Hn * 2;               // 32MB
  int smode = (ws_size >= HIST_OFF + STAMP_BYTES + xbytes) ? 1 : 0;
  const size_t slot_bytes = (size_t)2 * Bn * Hn * 2;            // 128KB
  int histok = (ws_size >= HIST_OFF + (size_t)513 * slot_bytes) ? 1 : 0;
  size_t xoff = smode ? (HIST_OFF + STAMP_BYTES)
                      : (HIST_OFF + (size_t)(histok ? 513 : 8) * slot_bytes);
  int xok = (ws_size >= xoff + xbytes) ? 1 : 0;

  // smode: zero the whole stamp region (stale stamps from prior replays are
  // semantically harmless — deterministic identical data — but zeroing keeps
  // replay timing honest). Else just the flag lines.
  hipMemsetAsync(d_ws, 0, smode ? (HIST_OFF + STAMP_BYTES) : HIST_OFF, stream);

  lstm_prep<<<dim3(2048), dim3(256), 0, stream>>>(x, hx, wsp, xok, smode, histok);

  void* args[] = {(void*)&x, (void*)&hx, (void*)&cx, (void*)&Wih, (void*)&Whh,
                  (void*)&bih, (void*)&bhh, (void*)&outp, (void*)&wsp,
                  (void*)&xok, (void*)&smode, (void*)&histok};
  hipError_t e = hipLaunchCooperativeKernel((const void*)lstm_fused, dim3(NWG),
                                            dim3(NTHR), args, 0, stream);
  if (e != hipSuccess) {
    lstm_fused<<<dim3(NWG), dim3(NTHR), 0, stream>>>(x, hx, cx, Wih, Whh, bih, bhh,
                                                     outp, wsp, xok, smode, histok);
  }
}

// Round 20
// 1748.375 us; speedup vs baseline: 2.5101x; 2.5101x over previous
//
#include <hip/hip_runtime.h>
#include <hip/hip_bf16.h>
#include <stdint.h>

#define Tn 512
#define Bn 64
#define Hn 512
#define LDP 520           // LDS row pitch (u16): 1040B
#define NWG 128
#define NTHR 512
#define BnHn (Bn * Hn)

typedef unsigned short u16;
typedef unsigned int u32;
typedef unsigned long long u64;
typedef __attribute__((ext_vector_type(8))) short bf16x8;
typedef __attribute__((ext_vector_type(4))) float f32x4;

// ws layout (bytes):
//   0     : flags[4 groups][32 cc] u32, 128B-aligned per group  (512B)
//   16384 : hist [nslot][2 layer][Bn][Hn] bf16  (nslot = 513 if histok else 8)
//   after : xbf [Tn][Bn][Hn] bf16 (32MB), if xok
#define HIST_OFF 16384

__device__ __forceinline__ u16 f2bf(float f) {
  u32 u = __float_as_uint(f);
  u = (u + 0x7FFFu + ((u >> 16) & 1u)) >> 16;   // RNE
  return (u16)u;
}
__device__ __forceinline__ float sigf(float x) { return 1.f / (1.f + __expf(-x)); }
__device__ __forceinline__ float mytanh(float x) {
  float e = __expf(2.f * x);
  return 1.f - 2.f / (e + 1.f);
}
__device__ __forceinline__ u32 ald32(const u32* p) {
  return __hip_atomic_load(p, __ATOMIC_RELAXED, __HIP_MEMORY_SCOPE_AGENT);
}

// ---------- pre-kernel: x -> bf16, hx -> hist init slot ----------
extern "C" __global__ void __launch_bounds__(256)
lstm_prep(const float* __restrict__ x, const float* __restrict__ hx,
          u32* __restrict__ ws, int xok, int histok) {
  u16* hist = (u16*)((char*)ws + HIST_OFF);
  u16* xbf  = hist + (size_t)(histok ? 513 : 8) * 2 * BnHn;
  const int slot_init = histok ? 512 : 7;
  const int gt = blockIdx.x * 256 + threadIdx.x;   // 0..524287
  if (xok) {
#pragma unroll
    for (int i = 0; i < 8; ++i) {
      const int c = gt + (i << 19);                // float4 chunk id, 4194304 total
      const float4 v = *(const float4*)(x + (size_t)c * 4);
      const u64 pk = (u64)((u32)f2bf(v.x) | ((u32)f2bf(v.y) << 16)) |
                     ((u64)((u32)f2bf(v.z) | ((u32)f2bf(v.w) << 16)) << 32);
      *(u64*)(xbf + (size_t)c * 4) = pk;
    }
  }
  if (gt < 32768) {
    const int e0 = 2 * gt;
    const int l = e0 >> 15;
    const int off = e0 & 32767;
    const u32 pk = (u32)f2bf(hx[e0]) | ((u32)f2bf(hx[e0 + 1]) << 16);
    *(u32*)(hist + ((size_t)slot_init * 2 + l) * BnHn + off) = pk;
  }
}

// ---------- main persistent cooperative kernel ----------
extern "C" __global__ void __launch_bounds__(NTHR, 2)
lstm_fused(const float* __restrict__ x, const float* __restrict__ hx,
           const float* __restrict__ cx, const float* __restrict__ Wih,
           const float* __restrict__ Whh, const float* __restrict__ bih,
           const float* __restrict__ bhh, float* __restrict__ out,
           u32* __restrict__ ws, int xok, int histok) {
  __shared__ u16 sh_inp[32 * LDP];
  __shared__ u16 sh_h[32 * LDP];

  // one-time L1/L2 invalidate: drop any lines poisoned (0xAA) between launches
  __builtin_amdgcn_fence(__ATOMIC_ACQUIRE, "agent");

  const int wg = blockIdx.x;
  const int tid = threadIdx.x;
  const int layer = wg >> 6;        // 0..1
  const int rem = wg & 63;
  const int shalf = rem >> 5;       // batch half: samples 0-31 / 32-63
  const int cc = rem & 31;          // 16-column chunk
  const int wave = tid >> 6;        // 0..7
  const int lane = tid & 63;
  const int l15 = lane & 15;
  const int lhi = lane >> 4;
  const int mt = wave >> 1;         // 0..3 gate-row tile
  const int nt = wave & 1;          // 0..1 sample tile

  u32* flags = ws;                  // flags[g*32 + cc], 128B-aligned per group
  u16* hist  = (u16*)((char*)ws + HIST_OFF);
  u16* xbf   = hist + (size_t)(histok ? 513 : 8) * 2 * BnHn;
  const int init_slot = histok ? 512 : 7;
  const int gid = layer * 2 + shalf;

  // ---- weights -> registers. WG rows (64): j = col*4 + gate, col base cc*16 ----
  const int jrow = mt * 16 + l15;
  const int gateA = jrow & 3, colA = jrow >> 2;
  const int growA = gateA * Hn + cc * 16 + colA;
  const float* wihp = Wih + ((size_t)layer * 4 * Hn + growA) * Hn;
  const float* whhp = Whh + ((size_t)layer * 4 * Hn + growA) * Hn;
  bf16x8 wih_f[16], whh_f[16];
#pragma unroll
  for (int kt = 0; kt < 16; ++kt) {
    const int k0 = kt * 32 + lhi * 8;
    const float4 va0 = *(const float4*)(wihp + k0);
    const float4 va1 = *(const float4*)(wihp + k0 + 4);
    const float4 vb0 = *(const float4*)(whhp + k0);
    const float4 vb1 = *(const float4*)(whhp + k0 + 4);
    bf16x8 a, b;
    a[0]=(short)f2bf(va0.x); a[1]=(short)f2bf(va0.y); a[2]=(short)f2bf(va0.z); a[3]=(short)f2bf(va0.w);
    a[4]=(short)f2bf(va1.x); a[5]=(short)f2bf(va1.y); a[6]=(short)f2bf(va1.z); a[7]=(short)f2bf(va1.w);
    b[0]=(short)f2bf(vb0.x); b[1]=(short)f2bf(vb0.y); b[2]=(short)f2bf(vb0.z); b[3]=(short)f2bf(vb0.w);
    b[4]=(short)f2bf(vb1.x); b[5]=(short)f2bf(vb1.y); b[6]=(short)f2bf(vb1.z); b[7]=(short)f2bf(vb1.w);
    wih_f[kt] = a; whh_f[kt] = b;
  }

  // ---- elementwise lane mapping: acc reg r == gate r for (sampE, colE) ----
  const int colE = cc * 16 + mt * 4 + lhi;
  const int sampE = shalf * 32 + nt * 16 + l15;
  float bias[4];
#pragma unroll
  for (int r = 0; r < 4; ++r) {
    const int grow = r * Hn + cc * 16 + mt * 4 + lhi;
    bias[r] = bih[layer * 4 * Hn + grow] + bhh[layer * 4 * Hn + grow];
  }
  float c_cur = cx[((size_t)layer * Bn + sampE) * Hn + colE];

  // ---- packed flat-poll lane mapping (edge semantics identical to R17) ----
  // L1 lags 3 -> cross RAW (L1 polls L0, tgtoff=1). histok: L0 has no cross
  // edge (monotonic hist) -> duplicate own. fallback 8-ring: L0 WAR tgtoff=1.
  int pidx, tgtoff;
  if (layer == 0) {
    if (lane < 32) { pidx = (0 * 2 + shalf) * 32 + lane; tgtoff = 0; }
    else if (histok) { pidx = (0 * 2 + shalf) * 32 + (lane - 32); tgtoff = 0; }
    else { pidx = (1 * 2 + shalf) * 32 + (lane - 32); tgtoff = 1; }
  } else {
    if (lane < 32) { pidx = (1 * 2 + shalf) * 32 + lane; tgtoff = 0; }
    else { pidx = (0 * 2 + shalf) * 32 + (lane - 32); tgtoff = 1; }
  }
  const u32* pollp = &flags[pidx];

  // stage x(t) -> sh_inp (layer 0); plain loads, coherent via prep boundary
  auto stage_x = [&](int t) {
    if (xok) {
      const u16* ip = xbf + ((size_t)t * Bn + shalf * 32) * Hn;
#pragma unroll
      for (int i = 0; i < 4; ++i) {
        const int chunk = tid + i * 512;             // 2048 chunks of 8 bf16
        const int row = chunk >> 6, c0 = (chunk & 63) * 8;
        const uint4 v = *(const uint4*)(ip + (size_t)row * Hn + c0);
        *(uint4*)(&sh_inp[row * LDP + c0]) = v;
      }
    } else {
      const float* xp = x + ((size_t)t * Bn + shalf * 32) * Hn;
#pragma unroll
      for (int i = 0; i < 8; ++i) {
        const int chunk = tid + i * 512;             // 4096 chunks of 4 floats
        const int row = chunk >> 7, c0 = (chunk & 127) * 4;
        const float4 v = *(const float4*)(xp + (size_t)row * Hn + c0);
        const u32 p0 = (u32)f2bf(v.x) | ((u32)f2bf(v.y) << 16);
        const u32 p1 = (u32)f2bf(v.z) | ((u32)f2bf(v.w) << 16);
        *(uint2*)(&sh_inp[row * LDP + c0]) = make_uint2(p0, p1);
      }
    }
  };
  // stage hist plane (slot, srclayer) -> LDS buffer
  auto stage_h = [&](int slot, int srclayer, u16* dst) {
    const u16* hp = hist + ((size_t)slot * 2 + srclayer) * BnHn + (size_t)(shalf * 32) * Hn;
    if (histok) {
#pragma unroll
      for (int i = 0; i < 4; ++i) {
        const int chunk = tid + i * 512;             // 2048 chunks of 16B (L2-cacheable)
        const int row = chunk >> 6, c0 = (chunk & 63) * 8;
        const uint4 v = *(const uint4*)(hp + (size_t)row * Hn + c0);
        *(uint4*)(&dst[row * LDP + c0]) = v;
      }
    } else {
#pragma unroll
      for (int i = 0; i < 8; ++i) {
        const int chunk = tid + i * 512;             // 4096 chunks of 8B (LLC-direct)
        const int row = chunk >> 7, c0 = (chunk & 127) * 4;
        const u64 v = __hip_atomic_load((const u64*)(hp + (size_t)row * Hn + c0),
                                        __ATOMIC_RELAXED, __HIP_MEMORY_SCOPE_AGENT);
        *(u64*)(&dst[row * LDP + c0]) = v;
      }
    }
  };
  // ih-GEMM from sh_inp into persistent accumulators (shadow-phase compute)
  f32x4 aI0 = {0.f,0.f,0.f,0.f}, aI1 = {0.f,0.f,0.f,0.f};
  auto compute_aI = [&]() {
    f32x4 t0 = {0.f,0.f,0.f,0.f}, t1 = {0.f,0.f,0.f,0.f};
    const int brow = (nt * 16 + l15) * LDP;
#pragma unroll
    for (int kt = 0; kt < 16; kt += 2) {
      const bf16x8 bi0 = *(const bf16x8*)(&sh_inp[brow + kt * 32 + lhi * 8]);
      const bf16x8 bi1 = *(const bf16x8*)(&sh_inp[brow + (kt + 1) * 32 + lhi * 8]);
      t0 = __builtin_amdgcn_mfma_f32_16x16x32_bf16(wih_f[kt], bi0, t0, 0, 0, 0);
      t1 = __builtin_amdgcn_mfma_f32_16x16x32_bf16(wih_f[kt + 1], bi1, t1, 0, 0, 0);
    }
    aI0 = t0; aI1 = t1;
  };

  // ---- pre-loop: L0 stages x(0) and precomputes aI(0) ----
  if (layer == 0) stage_x(0);
  __syncthreads();
  if (layer == 0) compute_aI();

  const int smax = Tn + 2;           // L1 lags 3 (t = s-3); L0 idles s >= Tn
  u32 ep = 0;
  for (int s = 0; s <= smax; ++s) {
    const int t = layer ? s - 3 : s;
    const bool act = (t >= 0) && (t < Tn);

    // ---------- critical phase: restage own h(t-1), hh-GEMM, elementwise ----------
    if (act) {
      const int slotR = (t == 0) ? init_slot : (histok ? (t - 1) : ((t - 1) & 7));
      stage_h(slotR, layer, sh_h);
    }
    __syncthreads();

    float hn = 0.f, cn = 0.f;
    if (act) {
      f32x4 b0 = {0,0,0,0}, b1 = {0,0,0,0};
      const int brow = (nt * 16 + l15) * LDP;
#pragma unroll
      for (int kt = 0; kt < 16; kt += 2) {
        const bf16x8 bh0 = *(const bf16x8*)(&sh_h[brow + kt * 32 + lhi * 8]);
        const bf16x8 bh1 = *(const bf16x8*)(&sh_h[brow + (kt + 1) * 32 + lhi * 8]);
        b0 = __builtin_amdgcn_mfma_f32_16x16x32_bf16(whh_f[kt], bh0, b0, 0, 0, 0);
        b1 = __builtin_amdgcn_mfma_f32_16x16x32_bf16(whh_f[kt + 1], bh1, b1, 0, 0, 0);
      }
      const float gi = aI0[0] + aI1[0] + b0[0] + b1[0] + bias[0];
      const float gf = aI0[1] + aI1[1] + b0[1] + b1[1] + bias[1];
      const float gg = aI0[2] + aI1[2] + b0[2] + b1[2] + bias[2];
      const float go_ = aI0[3] + aI1[3] + b0[3] + b1[3] + bias[3];
      cn = sigf(gf) * c_cur + sigf(gi) * mytanh(gg);
      hn = sigf(go_) * mytanh(cn);
      c_cur = cn;

      // pack 4 cols (lhi 0..3, same sample) -> 8B agent store into hist slot(t)
      const u32 hu = (u32)f2bf(hn);
      const u32 pair = hu | (__shfl_xor(hu, 16) << 16);
      const u32 hi2 = __shfl_xor(pair, 32);
      if (lhi == 0) {
        const int slotW = histok ? t : (t & 7);
        const u64 v8 = (u64)pair | ((u64)hi2 << 32);
        u16* wp = hist + ((size_t)slotW * 2 + layer) * BnHn + (size_t)sampE * Hn + cc * 16 + mt * 4;
        __hip_atomic_store((u64*)wp, v8, __ATOMIC_RELAXED, __HIP_MEMORY_SCOPE_AGENT);
      }
    }
    // drain h stores, join WG, signal own packed flag (relaxed; proven protocol)
    asm volatile("s_waitcnt vmcnt(0)" ::: "memory");
    __syncthreads();
    ++ep;
    if (tid == 0)
      __hip_atomic_store(&flags[gid * 32 + cc], ep,
                         __ATOMIC_RELAXED, __HIP_MEMORY_SCOPE_AGENT);

    // ---------- shadow phase: outputs + next-step input staging + ih-GEMM ----------
    if (act) {
      if (layer == 1)
        out[((size_t)t * Bn + sampE) * Hn + colE] = hn;
      if (t == Tn - 1) {
        out[(size_t)Tn * Bn * Hn + ((size_t)layer * Bn + sampE) * Hn + colE] = hn;
        out[(size_t)Tn * Bn * Hn + (size_t)2 * Bn * Hn + ((size_t)layer * Bn + sampE) * Hn + colE] = cn;
      }
    }
    bool ihnext = false;
    if (layer == 0) {
      if (s + 1 < Tn) { stage_x(s + 1); ihnext = true; }
    } else {
      const int u = s - 2;           // next step's input h0(u); guaranteed drained
      if (u >= 0 && u < Tn) {        // by the tgtoff=1 cross-check at end of loop s-1
        const int slotI = histok ? u : (u & 7);
        stage_h(slotI, 0, sh_inp);
        ihnext = true;
      }
    }
    __syncthreads();                 // sh_inp staged before ih-GEMM reads
    if (ihnext) compute_aI();

    if (s == smax) break;            // nobody depends on the final barrier

    // ---- packed flat barrier: ALL waves hot-poll 2-4 coalesced lines ----
    // Safe without a post-poll __syncthreads: every wave passed the pre-signal
    // __syncthreads (all sh_h reads done) before any wave can detect and begin
    // restage-writes; the post-restage __syncthreads re-joins before reads.
    while (true) {
      const u32 v = ald32(pollp);
      if (__all((int)(v + (u32)tgtoff >= ep))) break;
    }
    asm volatile("" ::: "memory");   // keep next restage loads after the poll
  }
}

extern "C" void kernel_launch(void* const* d_in, const int* in_sizes, int n_in,
                              void* d_out, int out_size, void* d_ws, size_t ws_size,
                              hipStream_t stream) {
  const float* x   = (const float*)d_in[0];
  const float* hx  = (const float*)d_in[1];
  const float* cx  = (const float*)d_in[2];
  const float* Wih = (const float*)d_in[3];
  const float* Whh = (const float*)d_in[4];
  const float* bih = (const float*)d_in[5];
  const float* bhh = (const float*)d_in[6];
  float* outp = (float*)d_out;
  u32* wsp = (u32*)d_ws;

  const size_t slot_bytes = (size_t)2 * Bn * Hn * 2;            // 128KB per t-slot
  int histok = (ws_size >= HIST_OFF + (size_t)513 * slot_bytes) ? 1 : 0;
  const size_t xoff = HIST_OFF + (size_t)(histok ? 513 : 8) * slot_bytes;
  int xok = (ws_size >= xoff + (size_t)Tn * Bn * Hn * 2) ? 1 : 0;

  hipMemsetAsync(d_ws, 0, HIST_OFF, stream);   // zero flag lines every call

  lstm_prep<<<dim3(2048), dim3(256), 0, stream>>>(x, hx, wsp, xok, histok);

  void* args[] = {(void*)&x, (void*)&hx, (void*)&cx, (void*)&Wih, (void*)&Whh,
                  (void*)&bih, (void*)&bhh, (void*)&outp, (void*)&wsp,
                  (void*)&xok, (void*)&histok};
  hipError_t e = hipLaunchCooperativeKernel((const void*)lstm_fused, dim3(NWG),
                                            dim3(NTHR), args, 0, stream);
  if (e != hipSuccess) {
    lstm_fused<<<dim3(NWG), dim3(NTHR), 0, stream>>>(x, hx, cx, Wih, Whh, bih, bhh,
                                                     outp, wsp, xok, histok);
  }
}